// Round 11
// baseline (77.475 us; speedup 1.0000x reference)
//
#include <hip/hip_runtime.h>
#include <math.h>

// HierarchicalPooling collapsed pipeline, round 11.
// N=32768, D=256, S=4, H=8, DH=32, CS=3276, C=11.
// R10 lesson: 261 blocks = 1 block/CU = 2 waves/SIMD — occupancy-starved; the
// LDS x-tile forced big blocks. R11 (kbd8): NO x staging at all — pass-1 A
// fragments and pass-2 x stream from global (f32, coalesced, L1/L2-served);
// LDS = sw+psb = 11.2KB; 64-node chunks -> 521 blocks = 2-3 blocks/CU.
// Pass-2 wave owns a d-slice (no cross-wave x redundancy). kln folded into kf2.

namespace {
constexpr int N   = 32768;
constexpr int CS  = 3276;
constexpr int CPC = 52;                // 64-node chunks per full cluster
constexpr int NB  = CPC*10 + 1;        // 521 blocks

// ws layout (float offsets); total ~17.6 MB
constexpr size_t CQ_OFF   = 0;                               // 32
constexpr size_t WQBF_OFF = 32;                              // 1024 uint4 B-fragments
constexpr size_t PART_OFF = WQBF_OFF + 4096;                 // NB*8192 chunk xw partials
constexpr size_t PS_OFF   = PART_OFF + (size_t)NB*8192;      // 11*32 sum-exp (atomic)
constexpr size_t XW_OFF   = PS_OFF + 352;                    // 11*8192 normalized xw
constexpr size_t PL_OFF   = XW_OFF + 90112;                  // 11*1024 pooled
constexpr size_t OL_OFF   = PL_OFF + 11264;                  // 11*1024 out rows
constexpr size_t HP_OFF   = OL_OFF + 11264;                  // 11*4*256 Wf1 partials
constexpr size_t FP_OFF   = HP_OFF + 11264;                  // 11*4*256 Wf2 partials
}

typedef __attribute__((ext_vector_type(8))) short short8;
typedef __attribute__((ext_vector_type(4))) float f32x4;

__device__ __forceinline__ unsigned f2bf(float f){    // f32 -> bf16 bits, RNE
  unsigned u = __float_as_uint(f);
  unsigned r = u + 0x7FFFu + ((u >> 16) & 1u);
  return r >> 16;
}

// ---- KA: wq rows -> bf16 B-fragments (packed via LDS); cq; PS zero. (R10-proven)
__global__ __launch_bounds__(256) void ka(const float* __restrict__ Wk, const float* __restrict__ bk,
                                          const float* __restrict__ pq, float* __restrict__ ws){
  int b = blockIdx.x, t = threadIdx.x;
  const float scale = 0.17677669529663688f;   // 32^-0.5
  if (b < 32){
    __shared__ float row[256];
    int s = b >> 3, h = b & 7;
    const float* wrow = Wk + ((size_t)s<<16) + (size_t)t*256 + h*32;
    const float* q = pq + (s*8 + h)*32;
    float a = 0.f;
#pragma unroll
    for (int j=0;j<32;j++) a = fmaf(wrow[j], q[j], a);
    row[t] = a*scale;
    __syncthreads();
    if (t < 32){
      int ks = t & 7, kg2 = t >> 3;
      const float* src = row + ks*32 + kg2*8;
      uint4 p;
      p.x = f2bf(src[0]) | (f2bf(src[1]) << 16);
      p.y = f2bf(src[2]) | (f2bf(src[3]) << 16);
      p.z = f2bf(src[4]) | (f2bf(src[5]) << 16);
      p.w = f2bf(src[6]) | (f2bf(src[7]) << 16);
      int Nt = b >> 4, l15b = b & 15;
      ((uint4*)(ws + WQBF_OFF))[(size_t)(Nt*8 + ks)*64 + l15b + 16*kg2] = p;
    }
  } else {
    if (t < 32){
      int s = t >> 3, h = t & 7;
      const float* br = bk + s*256 + h*32;
      const float* q = pq + t*32;
      float a = 0.f;
#pragma unroll
      for (int j=0;j<32;j++) a = fmaf(br[j], q[j], a);
      ws[CQ_OFF + t] = a*scale;
    }
    for (int i = t; i < 352; i += 256) ws[PS_OFF + i] = 0.f;   // zero atomic targets
  }
}

// ---- KBD8: MFMA scores + exp + PS atomics + xw chunk partials — NO x staging.
// 521 blocks x 512 threads; LDS = sw(9.2KB) + psb(2KB).
__global__ __launch_bounds__(512,4) void kbd8(const float* __restrict__ x, float* __restrict__ ws){
  int b = blockIdx.x, t = threadIdx.x;
  int c  = (b < 520) ? (b / CPC) : 10;
  int wi = (b < 520) ? (b % CPC) : 0;
  int n0 = c*CS + wi*64;
  int n1 = min(n0 + 64, min((c+1)*CS, N));
  int cnt = n1 - n0;                    // 64, 12 (cluster tails), or 8 (cluster 10)

  __shared__ float sw[64*36];           // exp-weights
  __shared__ float psb[16*32];

  int wv = t >> 6, lane = t & 63;
  // ---- pass 1: scores via MFMA; wave (Mt,Nt) = (wv&3, wv>>2)
  {
    int Mt = wv & 3, Nt = wv >> 2;
    int l15 = lane & 15, kg = lane >> 4;
    int grow = min(n0 + Mt*16 + l15, N-1);     // clamp tail OOB (masked later)
    const float* xrow = x + (size_t)grow*256;
    const uint4* WQBF4 = (const uint4*)(ws + WQBF_OFF);
    float cqv = ws[CQ_OFF + Nt*16 + l15];
    f32x4 acc1 = {0.f, 0.f, 0.f, 0.f};
#pragma unroll
    for (int ks=0; ks<8; ++ks){
      float4 x0 = *(const float4*)(xrow + ks*32 + kg*8);
      float4 x1 = *(const float4*)(xrow + ks*32 + kg*8 + 4);
      union { uint4 q; short8 v; } A, B;
      A.q.x = f2bf(x0.x) | (f2bf(x0.y) << 16);
      A.q.y = f2bf(x0.z) | (f2bf(x0.w) << 16);
      A.q.z = f2bf(x1.x) | (f2bf(x1.y) << 16);
      A.q.w = f2bf(x1.z) | (f2bf(x1.w) << 16);
      B.q = WQBF4[(size_t)(Nt*8 + ks)*64 + lane];   // L1-hot broadcast
      acc1 = __builtin_amdgcn_mfma_f32_16x16x32_bf16(A.v, B.v, acc1, 0, 0, 0);
    }
    // epilogue: C layout col(sh)=lane&15, row(j)=kg*4+reg
    int shc = Nt*16 + l15;
    float s4 = 0.f;
#pragma unroll
    for (int r=0;r<4;r++){
      int jl = Mt*16 + kg*4 + r;
      float e = __expf(acc1[r] + cqv);
      sw[jl*36 + shc] = e;
      if (jl < cnt) s4 += e;
    }
    psb[(Mt*4 + kg)*32 + shc] = s4;
  }
  __syncthreads();
  if (t < 32){
    float S = 0.f;
#pragma unroll
    for (int k=0;k<16;k++) S += psb[k*32 + t];
    unsafeAtomicAdd(ws + PS_OFF + (size_t)c*32 + t, S);
  }

  // ---- pass 2: xw partials; wave owns d-slice wv*32..+31 (f32 x from global).
  // lane: dqin = lane&7 (4 d each), shq = lane>>3 (4 sh each); acc[16].
  int dqin = lane & 7, shq = lane >> 3;
  int dbase = wv*32 + dqin*4;
  const float* xp = x + (size_t)n0*256 + dbase;
  float acc[16];
#pragma unroll
  for (int q=0;q<16;q++) acc[q] = 0.f;
#pragma unroll 8
  for (int j=0;j<cnt;++j){
    float4 xv = *(const float4*)(xp + (size_t)j*256);
    float4 wv2 = *(const float4*)(sw + j*36 + shq*4);
    acc[0]  = fmaf(wv2.x, xv.x, acc[0]);  acc[1]  = fmaf(wv2.x, xv.y, acc[1]);
    acc[2]  = fmaf(wv2.x, xv.z, acc[2]);  acc[3]  = fmaf(wv2.x, xv.w, acc[3]);
    acc[4]  = fmaf(wv2.y, xv.x, acc[4]);  acc[5]  = fmaf(wv2.y, xv.y, acc[5]);
    acc[6]  = fmaf(wv2.y, xv.z, acc[6]);  acc[7]  = fmaf(wv2.y, xv.w, acc[7]);
    acc[8]  = fmaf(wv2.z, xv.x, acc[8]);  acc[9]  = fmaf(wv2.z, xv.y, acc[9]);
    acc[10] = fmaf(wv2.z, xv.z, acc[10]); acc[11] = fmaf(wv2.z, xv.w, acc[11]);
    acc[12] = fmaf(wv2.w, xv.x, acc[12]); acc[13] = fmaf(wv2.w, xv.y, acc[13]);
    acc[14] = fmaf(wv2.w, xv.z, acc[14]); acc[15] = fmaf(wv2.w, xv.w, acc[15]);
  }
  float* pr = ws + PART_OFF + (size_t)b*8192;
#pragma unroll
  for (int i=0;i<4;i++)
    *(float4*)(pr + (size_t)(shq*4+i)*256 + dbase) =
      make_float4(acc[i*4], acc[i*4+1], acc[i*4+2], acc[i*4+3]);
}

// ---- KE2: sum chunk partials / PS -> xw[c][sh][d]. 352 blocks (R7-proven).
__global__ __launch_bounds__(256) void ke2(float* __restrict__ ws){
  int b = blockIdx.x, t = threadIdx.x;
  int c = b >> 5, sh = b & 31;
  int nch = (c < 10) ? CPC : 1;
  int cb  = (c < 10) ? c*CPC : 520;
  float rden = 1.0f / ws[PS_OFF + (size_t)c*32 + sh];
  const float* part = ws + PART_OFF + (size_t)sh*256 + t;
  float a = 0.f;
  for (int k=0;k<nch;k++) a += part[(size_t)(cb+k)*8192];
  ws[XW_OFF + (size_t)c*8192 + (size_t)sh*256 + t] = a * rden;
}

// ---- KP: pooled per (c,s,eq). 176 blocks (R7-proven).
__global__ __launch_bounds__(256) void kp(float* __restrict__ ws,
    const float* __restrict__ Wv, const float* __restrict__ bv){
  int b = blockIdx.x; int c = b >> 4, rem = b & 15, s = rem >> 2, eq = rem & 3;
  int t = threadIdx.x, e64 = t & 63, dq = t >> 6;
  int e = eq*64 + e64, h = e >> 5;
  const float* xr = ws + XW_OFF + (size_t)c*8192 + (size_t)(s*8 + h)*256 + dq*64;
  const float* wv = Wv + (size_t)s*65536 + (size_t)(dq*64)*256 + e;
  float a = 0.f;
#pragma unroll 8
  for (int d=0; d<64; ++d) a = fmaf(wv[(size_t)d*256], xr[d], a);
  __shared__ float red[4][64];
  red[dq][e64] = a;
  __syncthreads();
  if (t < 64){
    float rcnt = (c < 10) ? (1.0f/(float)CS) : 0.125f;
    float p = (red[0][t]+red[1][t]+red[2][t]+red[3][t] + bv[s*256 + eq*64 + t]) * rcnt;
    ws[PL_OFF + (size_t)c*1024 + s*256 + eq*64 + t] = p;
  }
}

// ---- KO: out per (c,s,eq) = pooled @ Wo + bo. 176 blocks (R7-proven).
__global__ __launch_bounds__(256) void ko(float* __restrict__ ws,
    const float* __restrict__ Wo, const float* __restrict__ bo){
  int b = blockIdx.x; int c = b >> 4, rem = b & 15, s = rem >> 2, eq = rem & 3;
  int t = threadIdx.x, e64 = t & 63, dq = t >> 6;
  int e = eq*64 + e64;
  const float* pr = ws + PL_OFF + (size_t)c*1024 + s*256 + dq*64;
  const float* wo = Wo + (size_t)s*65536 + (size_t)(dq*64)*256 + e;
  float a = 0.f;
#pragma unroll 8
  for (int d=0; d<64; ++d) a = fmaf(wo[(size_t)d*256], pr[d], a);
  __shared__ float red[4][64];
  red[dq][e64] = a;
  __syncthreads();
  if (t < 64)
    ws[OL_OFF + (size_t)c*1024 + s*256 + eq*64 + t] =
      red[0][t]+red[1][t]+red[2][t]+red[3][t] + bo[s*256 + eq*64 + t];
}

// ---- KF1: h partials: block (c, fq, kq). 176 blocks (R7-proven).
__global__ __launch_bounds__(256) void kf1(const float* __restrict__ Wf1, float* __restrict__ ws){
  int b = blockIdx.x; int c = b >> 4, fq = (b >> 2) & 3, kq = b & 3;
  int t = threadIdx.x, f64 = t & 63, ks = t >> 6;
  const float* ol = ws + OL_OFF + (size_t)c*1024 + kq*256 + ks*64;
  const float* wf = Wf1 + (size_t)(kq*256 + ks*64)*256 + fq*64 + f64;
  float a = 0.f;
#pragma unroll 8
  for (int i=0; i<64; ++i) a = fmaf(wf[(size_t)i*256], ol[i], a);
  __shared__ float red[4][64];
  red[ks][f64] = a;
  __syncthreads();
  if (t < 64)
    ws[HP_OFF + (size_t)(c*4 + kq)*256 + fq*64 + t] = red[0][t]+red[1][t]+red[2][t]+red[3][t];
}

// ---- KF2B: (LN+GELU recomputed in-block from HP) -> Wf2 partials. 176 blocks.
__global__ __launch_bounds__(256) void kf2b(const float* __restrict__ Wf2, float* __restrict__ ws,
    const float* __restrict__ bf1, const float* __restrict__ lng, const float* __restrict__ lnb){
  int b = blockIdx.x; int c = b >> 4, gq = (b >> 2) & 3, kq = b & 3;
  int t = threadIdx.x;
  __shared__ float hl[256];
  __shared__ float rs1[4], rs2[4];
  // recompute hl[c] (LN+GELU) from HP — 4KB L2 reads, block-local
  float hacc = bf1[t];
#pragma unroll
  for (int q=0;q<4;q++) hacc += ws[HP_OFF + (size_t)(c*4+q)*256 + t];
  float s1 = hacc, s2v = hacc*hacc;
  for (int off=32; off>0; off>>=1){ s1 += __shfl_down(s1, off, 64); s2v += __shfl_down(s2v, off, 64); }
  int wid = t>>6, lane = t&63;
  if (lane==0){ rs1[wid]=s1; rs2[wid]=s2v; }
  __syncthreads();
  float S1 = rs1[0]+rs1[1]+rs1[2]+rs1[3];
  float S2 = rs2[0]+rs2[1]+rs2[2]+rs2[3];
  float mu = S1*(1.0f/256.0f);
  float var = S2*(1.0f/256.0f) - mu*mu;
  float rsig = rsqrtf(var + 1e-5f);
  float hn = (hacc - mu)*rsig*lng[t] + lnb[t];
  hl[t] = 0.5f*hn*(1.0f + erff(hn*0.70710678118654752f));   // exact GELU
  __syncthreads();
  int g64 = t & 63, ks = t >> 6;
  const float* hh = hl + kq*64 + ks*16;
  const float* wf = Wf2 + (size_t)(kq*64 + ks*16)*256 + gq*64 + g64;
  float a = 0.f;
#pragma unroll
  for (int i=0; i<16; ++i) a = fmaf(wf[(size_t)i*256], hh[i], a);
  __shared__ float red[4][64];
  red[ks][g64] = a;
  __syncthreads();
  if (t < 64)
    ws[FP_OFF + (size_t)(c*4 + kq)*256 + gq*64 + t] = red[0][t]+red[1][t]+red[2][t]+red[3][t];
}

// ---- KBC2: sum Wf2 partials + bf2 once per block, broadcast. 8192 blocks (R7-proven).
__global__ __launch_bounds__(256) void kbc2(const float* __restrict__ ws, float4* __restrict__ out,
                                            const float* __restrict__ bf2){
  unsigned bidx = blockIdx.x, t = threadIdx.x;
  unsigned idx = bidx*256u + t;
  unsigned c = (bidx*4u) / (unsigned)CS;   // 3276 % 4 == 0 -> one cluster per block
  __shared__ float4 row[64];
  if (t < 64){
    const float4* FP4 = (const float4*)(ws + FP_OFF);
    float4 s0 = FP4[(c*4+0)*64 + t];
    float4 s1 = FP4[(c*4+1)*64 + t];
    float4 s2 = FP4[(c*4+2)*64 + t];
    float4 s3 = FP4[(c*4+3)*64 + t];
    float4 bb = ((const float4*)bf2)[t];
    row[t] = make_float4(s0.x+s1.x+s2.x+s3.x+bb.x, s0.y+s1.y+s2.y+s3.y+bb.y,
                         s0.z+s1.z+s2.z+s3.z+bb.z, s0.w+s1.w+s2.w+s3.w+bb.w);
  }
  __syncthreads();
  out[idx] = row[t & 63u];
}

extern "C" void kernel_launch(void* const* d_in, const int* in_sizes, int n_in,
                              void* d_out, int out_size, void* d_ws, size_t ws_size,
                              hipStream_t stream) {
  const float* x   = (const float*)d_in[0];
  // d_in[1] edge_index, d_in[2] batch: unused by the reference computation
  const float* Wk  = (const float*)d_in[3];
  const float* bk  = (const float*)d_in[4];
  const float* Wv  = (const float*)d_in[5];
  const float* bv  = (const float*)d_in[6];
  const float* Wo  = (const float*)d_in[7];
  const float* bo  = (const float*)d_in[8];
  const float* pq  = (const float*)d_in[9];
  const float* Wf1 = (const float*)d_in[10];
  const float* bf1 = (const float*)d_in[11];
  const float* lng = (const float*)d_in[12];
  const float* lnb = (const float*)d_in[13];
  const float* Wf2 = (const float*)d_in[14];
  const float* bf2 = (const float*)d_in[15];
  float* ws = (float*)d_ws;
  float4* out = (float4*)d_out;

  hipLaunchKernelGGL(ka,   dim3(33),   dim3(256), 0, stream, Wk, bk, pq, ws);
  hipLaunchKernelGGL(kbd8, dim3(NB),   dim3(512), 0, stream, x, ws);
  hipLaunchKernelGGL(ke2,  dim3(352),  dim3(256), 0, stream, ws);
  hipLaunchKernelGGL(kp,   dim3(176),  dim3(256), 0, stream, ws, Wv, bv);
  hipLaunchKernelGGL(ko,   dim3(176),  dim3(256), 0, stream, ws, Wo, bo);
  hipLaunchKernelGGL(kf1,  dim3(176),  dim3(256), 0, stream, Wf1, ws);
  hipLaunchKernelGGL(kf2b, dim3(176),  dim3(256), 0, stream, Wf2, ws, bf1, lng, lnb);
  hipLaunchKernelGGL(kbc2, dim3(8192), dim3(256), 0, stream, ws, out, bf2);
}

// Round 12
// 69.429 us; speedup vs baseline: 1.1159x; 1.1159x over previous
//
#include <hip/hip_runtime.h>
#include <math.h>

// HierarchicalPooling collapsed pipeline, round 12.
// N=32768, D=256, S=4, H=8, DH=32, CS=3276, C=11.
// R11 lesson: un-staged global streaming regressed (x traffic 3x through
// L1/L2); R10's bf16-LDS-tile kbd7 stays the winner but was block-count
// starved (261 blocks = 1/CU = 2 waves/SIMD).
// R12: kbd7 structure with CPN=64 -> 521 blocks (2 blocks/CU, 4 waves/SIMD),
// single subtile (no st-loop); kln folded into kf2 (R11-proven kf2b).

namespace {
constexpr int N   = 32768;
constexpr int CS  = 3276;
constexpr int CPC = 52;                // 64-node chunks per full cluster
constexpr int NB  = CPC*10 + 1;        // 521 blocks

// ws layout (float offsets); total ~17.6 MB
constexpr size_t CQ_OFF   = 0;                               // 32
constexpr size_t WQBF_OFF = 32;                              // 1024 uint4 B-fragments
constexpr size_t PART_OFF = WQBF_OFF + 4096;                 // NB*8192 chunk xw partials
constexpr size_t PS_OFF   = PART_OFF + (size_t)NB*8192;      // 11*32 sum-exp (atomic)
constexpr size_t XW_OFF   = PS_OFF + 352;                    // 11*8192 normalized xw
constexpr size_t PL_OFF   = XW_OFF + 90112;                  // 11*1024 pooled
constexpr size_t OL_OFF   = PL_OFF + 11264;                  // 11*1024 out rows
constexpr size_t HP_OFF   = OL_OFF + 11264;                  // 11*4*256 Wf1 partials
constexpr size_t FP_OFF   = HP_OFF + 11264;                  // 11*4*256 Wf2 partials
}

typedef __attribute__((ext_vector_type(8))) short short8;
typedef __attribute__((ext_vector_type(4))) float f32x4;

__device__ __forceinline__ unsigned f2bf(float f){    // f32 -> bf16 bits, RNE
  unsigned u = __float_as_uint(f);
  unsigned r = u + 0x7FFFu + ((u >> 16) & 1u);
  return r >> 16;
}

// ---- KA: wq rows -> bf16 B-fragments (packed via LDS); cq; PS zero. (R10-proven)
__global__ __launch_bounds__(256) void ka(const float* __restrict__ Wk, const float* __restrict__ bk,
                                          const float* __restrict__ pq, float* __restrict__ ws){
  int b = blockIdx.x, t = threadIdx.x;
  const float scale = 0.17677669529663688f;   // 32^-0.5
  if (b < 32){
    __shared__ float row[256];
    int s = b >> 3, h = b & 7;
    const float* wrow = Wk + ((size_t)s<<16) + (size_t)t*256 + h*32;
    const float* q = pq + (s*8 + h)*32;
    float a = 0.f;
#pragma unroll
    for (int j=0;j<32;j++) a = fmaf(wrow[j], q[j], a);
    row[t] = a*scale;
    __syncthreads();
    if (t < 32){
      int ks = t & 7, kg2 = t >> 3;
      const float* src = row + ks*32 + kg2*8;
      uint4 p;
      p.x = f2bf(src[0]) | (f2bf(src[1]) << 16);
      p.y = f2bf(src[2]) | (f2bf(src[3]) << 16);
      p.z = f2bf(src[4]) | (f2bf(src[5]) << 16);
      p.w = f2bf(src[6]) | (f2bf(src[7]) << 16);
      int Nt = b >> 4, l15b = b & 15;
      ((uint4*)(ws + WQBF_OFF))[(size_t)(Nt*8 + ks)*64 + l15b + 16*kg2] = p;
    }
  } else {
    if (t < 32){
      int s = t >> 3, h = t & 7;
      const float* br = bk + s*256 + h*32;
      const float* q = pq + t*32;
      float a = 0.f;
#pragma unroll
      for (int j=0;j<32;j++) a = fmaf(br[j], q[j], a);
      ws[CQ_OFF + t] = a*scale;
    }
    for (int i = t; i < 352; i += 256) ws[PS_OFF + i] = 0.f;   // zero atomic targets
  }
}

// ---- KBD9: MFMA scores + exp + PS atomics + xw chunk partials.
// 521 blocks x 512 threads; one 64-row bf16 subtile (R10 kbd7 structure, CPN=64).
__global__ __launch_bounds__(512,4) void kbd9(const float* __restrict__ x, float* __restrict__ ws){
  int b = blockIdx.x, t = threadIdx.x;
  int c  = (b < 520) ? (b / CPC) : 10;
  int wi = (b < 520) ? (b % CPC) : 0;
  int n0 = c*CS + wi*64;
  int n1 = min(n0 + 64, min((c+1)*CS, N));
  int cnt = n1 - n0;                    // 64, 12 (cluster tails), or 8 (cluster 10)

  __shared__ unsigned short xtb[64*264]; // 33.8 KB bf16 tile, row stride 528B
  __shared__ float sw[64*36];            // exp-weights (f32)
  __shared__ float psb[16*32];

  int wv = t >> 6, lane = t & 63;
  int Mt = wv & 3, Nt = wv >> 2;
  int l15 = lane & 15, kg = lane >> 4;
  int arow = Mt*16 + l15;
  uint4 bfr[8];
  const uint4* WQBF4 = (const uint4*)(ws + WQBF_OFF);
#pragma unroll
  for (int ks=0; ks<8; ++ks) bfr[ks] = WQBF4[(size_t)(Nt*8 + ks)*64 + lane];
  float cqv = ws[CQ_OFF + Nt*16 + l15];
  int shc = Nt*16 + l15;

  // stage 64 rows as bf16 (coalesced float4 loads, b64 LDS writes)
  const float4* X4 = (const float4*)x;
#pragma unroll
  for (int k=0;k<8;k++){
    int f = t + k*512;
    int j = f >> 6, c4 = f & 63;
    if (n0 + j < N){
      float4 v = X4[(size_t)(n0+j)*64 + c4];
      uint2 p;
      p.x = f2bf(v.x) | (f2bf(v.y) << 16);
      p.y = f2bf(v.z) | (f2bf(v.w) << 16);
      *(uint2*)(xtb + j*264 + c4*4) = p;
    }
  }
  __syncthreads();

  // pass 1: scores via 8x mfma_f32_16x16x32_bf16 (A read direct as bf16)
  f32x4 acc1 = {0.f, 0.f, 0.f, 0.f};
#pragma unroll
  for (int ks=0; ks<8; ++ks){
    union { uint4 q; short8 v; } A, B;
    A.q = *(const uint4*)(xtb + arow*264 + ks*32 + kg*8);
    B.q = bfr[ks];
    acc1 = __builtin_amdgcn_mfma_f32_16x16x32_bf16(A.v, B.v, acc1, 0, 0, 0);
  }
  // epilogue: C layout col(sh)=lane&15, row(j)=kg*4+reg
  float s4 = 0.f;
#pragma unroll
  for (int r=0;r<4;r++){
    int jl = Mt*16 + kg*4 + r;
    float e = __expf(acc1[r] + cqv);
    sw[jl*36 + shc] = e;
    if (jl < cnt) s4 += e;
  }
  psb[(Mt*4 + kg)*32 + shc] = s4;
  __syncthreads();
  if (t < 32){
    float S = 0.f;
#pragma unroll
    for (int k=0;k<16;k++) S += psb[k*32 + t];
    unsafeAtomicAdd(ws + PS_OFF + (size_t)c*32 + t, S);
  }

  // pass 2: xw accumulation, 4sh x 4d per thread (bf16 x, f32 weights/acc)
  int shq = t >> 6, dq = t & 63;
  float acc[16];
#pragma unroll
  for (int q=0;q<16;q++) acc[q] = 0.f;
#pragma unroll 4
  for (int j=0;j<cnt;++j){
    uint2 u = *(const uint2*)(xtb + j*264 + dq*4);
    float x0 = __uint_as_float(u.x << 16);
    float x1 = __uint_as_float(u.x & 0xffff0000u);
    float x2 = __uint_as_float(u.y << 16);
    float x3 = __uint_as_float(u.y & 0xffff0000u);
    float4 wv2 = *(const float4*)(sw + j*36 + shq*4);
    acc[0]  = fmaf(wv2.x, x0, acc[0]);  acc[1]  = fmaf(wv2.x, x1, acc[1]);
    acc[2]  = fmaf(wv2.x, x2, acc[2]);  acc[3]  = fmaf(wv2.x, x3, acc[3]);
    acc[4]  = fmaf(wv2.y, x0, acc[4]);  acc[5]  = fmaf(wv2.y, x1, acc[5]);
    acc[6]  = fmaf(wv2.y, x2, acc[6]);  acc[7]  = fmaf(wv2.y, x3, acc[7]);
    acc[8]  = fmaf(wv2.z, x0, acc[8]);  acc[9]  = fmaf(wv2.z, x1, acc[9]);
    acc[10] = fmaf(wv2.z, x2, acc[10]); acc[11] = fmaf(wv2.z, x3, acc[11]);
    acc[12] = fmaf(wv2.w, x0, acc[12]); acc[13] = fmaf(wv2.w, x1, acc[13]);
    acc[14] = fmaf(wv2.w, x2, acc[14]); acc[15] = fmaf(wv2.w, x3, acc[15]);
  }
  // partial store (coalesced b128)
  float* pr = ws + PART_OFF + (size_t)b*8192;
#pragma unroll
  for (int i=0;i<4;i++)
    *(float4*)(pr + (size_t)(shq*4+i)*256 + dq*4) =
      make_float4(acc[i*4], acc[i*4+1], acc[i*4+2], acc[i*4+3]);
}

// ---- KE2: sum chunk partials / PS -> xw[c][sh][d]. 352 blocks (R7-proven).
__global__ __launch_bounds__(256) void ke2(float* __restrict__ ws){
  int b = blockIdx.x, t = threadIdx.x;
  int c = b >> 5, sh = b & 31;
  int nch = (c < 10) ? CPC : 1;
  int cb  = (c < 10) ? c*CPC : 520;
  float rden = 1.0f / ws[PS_OFF + (size_t)c*32 + sh];
  const float* part = ws + PART_OFF + (size_t)sh*256 + t;
  float a = 0.f;
  for (int k=0;k<nch;k++) a += part[(size_t)(cb+k)*8192];
  ws[XW_OFF + (size_t)c*8192 + (size_t)sh*256 + t] = a * rden;
}

// ---- KP: pooled per (c,s,eq). 176 blocks (R7-proven).
__global__ __launch_bounds__(256) void kp(float* __restrict__ ws,
    const float* __restrict__ Wv, const float* __restrict__ bv){
  int b = blockIdx.x; int c = b >> 4, rem = b & 15, s = rem >> 2, eq = rem & 3;
  int t = threadIdx.x, e64 = t & 63, dq = t >> 6;
  int e = eq*64 + e64, h = e >> 5;
  const float* xr = ws + XW_OFF + (size_t)c*8192 + (size_t)(s*8 + h)*256 + dq*64;
  const float* wv = Wv + (size_t)s*65536 + (size_t)(dq*64)*256 + e;
  float a = 0.f;
#pragma unroll 8
  for (int d=0; d<64; ++d) a = fmaf(wv[(size_t)d*256], xr[d], a);
  __shared__ float red[4][64];
  red[dq][e64] = a;
  __syncthreads();
  if (t < 64){
    float rcnt = (c < 10) ? (1.0f/(float)CS) : 0.125f;
    float p = (red[0][t]+red[1][t]+red[2][t]+red[3][t] + bv[s*256 + eq*64 + t]) * rcnt;
    ws[PL_OFF + (size_t)c*1024 + s*256 + eq*64 + t] = p;
  }
}

// ---- KO: out per (c,s,eq) = pooled @ Wo + bo. 176 blocks (R7-proven).
__global__ __launch_bounds__(256) void ko(float* __restrict__ ws,
    const float* __restrict__ Wo, const float* __restrict__ bo){
  int b = blockIdx.x; int c = b >> 4, rem = b & 15, s = rem >> 2, eq = rem & 3;
  int t = threadIdx.x, e64 = t & 63, dq = t >> 6;
  int e = eq*64 + e64;
  const float* pr = ws + PL_OFF + (size_t)c*1024 + s*256 + dq*64;
  const float* wo = Wo + (size_t)s*65536 + (size_t)(dq*64)*256 + e;
  float a = 0.f;
#pragma unroll 8
  for (int d=0; d<64; ++d) a = fmaf(wo[(size_t)d*256], pr[d], a);
  __shared__ float red[4][64];
  red[dq][e64] = a;
  __syncthreads();
  if (t < 64)
    ws[OL_OFF + (size_t)c*1024 + s*256 + eq*64 + t] =
      red[0][t]+red[1][t]+red[2][t]+red[3][t] + bo[s*256 + eq*64 + t];
}

// ---- KF1: h partials: block (c, fq, kq). 176 blocks (R7-proven).
__global__ __launch_bounds__(256) void kf1(const float* __restrict__ Wf1, float* __restrict__ ws){
  int b = blockIdx.x; int c = b >> 4, fq = (b >> 2) & 3, kq = b & 3;
  int t = threadIdx.x, f64 = t & 63, ks = t >> 6;
  const float* ol = ws + OL_OFF + (size_t)c*1024 + kq*256 + ks*64;
  const float* wf = Wf1 + (size_t)(kq*256 + ks*64)*256 + fq*64 + f64;
  float a = 0.f;
#pragma unroll 8
  for (int i=0; i<64; ++i) a = fmaf(wf[(size_t)i*256], ol[i], a);
  __shared__ float red[4][64];
  red[ks][f64] = a;
  __syncthreads();
  if (t < 64)
    ws[HP_OFF + (size_t)(c*4 + kq)*256 + fq*64 + t] = red[0][t]+red[1][t]+red[2][t]+red[3][t];
}

// ---- KF2B: (LN+GELU recomputed in-block from HP) -> Wf2 partials. 176 blocks (R11-proven).
__global__ __launch_bounds__(256) void kf2b(const float* __restrict__ Wf2, float* __restrict__ ws,
    const float* __restrict__ bf1, const float* __restrict__ lng, const float* __restrict__ lnb){
  int b = blockIdx.x; int c = b >> 4, gq = (b >> 2) & 3, kq = b & 3;
  int t = threadIdx.x;
  __shared__ float hl[256];
  __shared__ float rs1[4], rs2[4];
  float hacc = bf1[t];
#pragma unroll
  for (int q=0;q<4;q++) hacc += ws[HP_OFF + (size_t)(c*4+q)*256 + t];
  float s1 = hacc, s2v = hacc*hacc;
  for (int off=32; off>0; off>>=1){ s1 += __shfl_down(s1, off, 64); s2v += __shfl_down(s2v, off, 64); }
  int wid = t>>6, lane = t&63;
  if (lane==0){ rs1[wid]=s1; rs2[wid]=s2v; }
  __syncthreads();
  float S1 = rs1[0]+rs1[1]+rs1[2]+rs1[3];
  float S2 = rs2[0]+rs2[1]+rs2[2]+rs2[3];
  float mu = S1*(1.0f/256.0f);
  float var = S2*(1.0f/256.0f) - mu*mu;
  float rsig = rsqrtf(var + 1e-5f);
  float hn = (hacc - mu)*rsig*lng[t] + lnb[t];
  hl[t] = 0.5f*hn*(1.0f + erff(hn*0.70710678118654752f));   // exact GELU
  __syncthreads();
  int g64 = t & 63, ks = t >> 6;
  const float* hh = hl + kq*64 + ks*16;
  const float* wf = Wf2 + (size_t)(kq*64 + ks*16)*256 + gq*64 + g64;
  float a = 0.f;
#pragma unroll
  for (int i=0; i<16; ++i) a = fmaf(wf[(size_t)i*256], hh[i], a);
  __shared__ float red[4][64];
  red[ks][g64] = a;
  __syncthreads();
  if (t < 64)
    ws[FP_OFF + (size_t)(c*4 + kq)*256 + gq*64 + t] = red[0][t]+red[1][t]+red[2][t]+red[3][t];
}

// ---- KBC2: sum Wf2 partials + bf2 once per block, broadcast. 8192 blocks (R7-proven).
__global__ __launch_bounds__(256) void kbc2(const float* __restrict__ ws, float4* __restrict__ out,
                                            const float* __restrict__ bf2){
  unsigned bidx = blockIdx.x, t = threadIdx.x;
  unsigned idx = bidx*256u + t;
  unsigned c = (bidx*4u) / (unsigned)CS;   // 3276 % 4 == 0 -> one cluster per block
  __shared__ float4 row[64];
  if (t < 64){
    const float4* FP4 = (const float4*)(ws + FP_OFF);
    float4 s0 = FP4[(c*4+0)*64 + t];
    float4 s1 = FP4[(c*4+1)*64 + t];
    float4 s2 = FP4[(c*4+2)*64 + t];
    float4 s3 = FP4[(c*4+3)*64 + t];
    float4 bb = ((const float4*)bf2)[t];
    row[t] = make_float4(s0.x+s1.x+s2.x+s3.x+bb.x, s0.y+s1.y+s2.y+s3.y+bb.y,
                         s0.z+s1.z+s2.z+s3.z+bb.z, s0.w+s1.w+s2.w+s3.w+bb.w);
  }
  __syncthreads();
  out[idx] = row[t & 63u];
}

extern "C" void kernel_launch(void* const* d_in, const int* in_sizes, int n_in,
                              void* d_out, int out_size, void* d_ws, size_t ws_size,
                              hipStream_t stream) {
  const float* x   = (const float*)d_in[0];
  // d_in[1] edge_index, d_in[2] batch: unused by the reference computation
  const float* Wk  = (const float*)d_in[3];
  const float* bk  = (const float*)d_in[4];
  const float* Wv  = (const float*)d_in[5];
  const float* bv  = (const float*)d_in[6];
  const float* Wo  = (const float*)d_in[7];
  const float* bo  = (const float*)d_in[8];
  const float* pq  = (const float*)d_in[9];
  const float* Wf1 = (const float*)d_in[10];
  const float* bf1 = (const float*)d_in[11];
  const float* lng = (const float*)d_in[12];
  const float* lnb = (const float*)d_in[13];
  const float* Wf2 = (const float*)d_in[14];
  const float* bf2 = (const float*)d_in[15];
  float* ws = (float*)d_ws;
  float4* out = (float4*)d_out;

  hipLaunchKernelGGL(ka,   dim3(33),   dim3(256), 0, stream, Wk, bk, pq, ws);
  hipLaunchKernelGGL(kbd9, dim3(NB),   dim3(512), 0, stream, x, ws);
  hipLaunchKernelGGL(ke2,  dim3(352),  dim3(256), 0, stream, ws);
  hipLaunchKernelGGL(kp,   dim3(176),  dim3(256), 0, stream, ws, Wv, bv);
  hipLaunchKernelGGL(ko,   dim3(176),  dim3(256), 0, stream, ws, Wo, bo);
  hipLaunchKernelGGL(kf1,  dim3(176),  dim3(256), 0, stream, Wf1, ws);
  hipLaunchKernelGGL(kf2b, dim3(176),  dim3(256), 0, stream, Wf2, ws, bf1, lng, lnb);
  hipLaunchKernelGGL(kbc2, dim3(8192), dim3(256), 0, stream, ws, out, bf2);
}

// Round 13
// 61.758 us; speedup vs baseline: 1.2545x; 1.1242x over previous
//
#include <hip/hip_runtime.h>
#include <math.h>

// HierarchicalPooling collapsed pipeline, round 13.
// N=32768, D=256, S=4, H=8, DH=32, CS=3276, C=11.
// R12 lesson: kbd ~35us dominated by scalar pass-2 (64x b64+b128 per wave,
// LDS-pipe bound). R13: pass-2 -> MFMA (O[sh][d] = sum_j w[j][sh] x[j][d]):
// A = swT (bf16, b64-written in pass-1 epilogue, b128-read), B = x via
// ds_read_b64_tr_b16 (HW transpose read; lane l addr -> x[j0+8g+e][d=Nt*16+w]).
// Rule #18: tr asm reads then s_waitcnt lgkmcnt(0) + sched_barrier(0) then MFMAs.
// Rest-chain identical to R12.

namespace {
constexpr int N   = 32768;
constexpr int CS  = 3276;
constexpr int CPC = 52;                // 64-node chunks per full cluster
constexpr int NB  = CPC*10 + 1;        // 521 blocks

// ws layout (float offsets); total ~17.6 MB
constexpr size_t CQ_OFF   = 0;                               // 32
constexpr size_t WQBF_OFF = 32;                              // 1024 uint4 B-fragments
constexpr size_t PART_OFF = WQBF_OFF + 4096;                 // NB*8192 chunk xw partials
constexpr size_t PS_OFF   = PART_OFF + (size_t)NB*8192;      // 11*32 sum-exp (atomic)
constexpr size_t XW_OFF   = PS_OFF + 352;                    // 11*8192 normalized xw
constexpr size_t PL_OFF   = XW_OFF + 90112;                  // 11*1024 pooled
constexpr size_t OL_OFF   = PL_OFF + 11264;                  // 11*1024 out rows
constexpr size_t HP_OFF   = OL_OFF + 11264;                  // 11*4*256 Wf1 partials
constexpr size_t FP_OFF   = HP_OFF + 11264;                  // 11*4*256 Wf2 partials
}

typedef __attribute__((ext_vector_type(8))) short short8;
typedef __attribute__((ext_vector_type(4))) float f32x4;

__device__ __forceinline__ unsigned f2bf(float f){    // f32 -> bf16 bits, RNE
  unsigned u = __float_as_uint(f);
  unsigned r = u + 0x7FFFu + ((u >> 16) & 1u);
  return r >> 16;
}

// ---- KA: wq rows -> bf16 B-fragments (packed via LDS); cq; PS zero. (R10-proven)
__global__ __launch_bounds__(256) void ka(const float* __restrict__ Wk, const float* __restrict__ bk,
                                          const float* __restrict__ pq, float* __restrict__ ws){
  int b = blockIdx.x, t = threadIdx.x;
  const float scale = 0.17677669529663688f;   // 32^-0.5
  if (b < 32){
    __shared__ float row[256];
    int s = b >> 3, h = b & 7;
    const float* wrow = Wk + ((size_t)s<<16) + (size_t)t*256 + h*32;
    const float* q = pq + (s*8 + h)*32;
    float a = 0.f;
#pragma unroll
    for (int j=0;j<32;j++) a = fmaf(wrow[j], q[j], a);
    row[t] = a*scale;
    __syncthreads();
    if (t < 32){
      int ks = t & 7, kg2 = t >> 3;
      const float* src = row + ks*32 + kg2*8;
      uint4 p;
      p.x = f2bf(src[0]) | (f2bf(src[1]) << 16);
      p.y = f2bf(src[2]) | (f2bf(src[3]) << 16);
      p.z = f2bf(src[4]) | (f2bf(src[5]) << 16);
      p.w = f2bf(src[6]) | (f2bf(src[7]) << 16);
      int Nt = b >> 4, l15b = b & 15;
      ((uint4*)(ws + WQBF_OFF))[(size_t)(Nt*8 + ks)*64 + l15b + 16*kg2] = p;
    }
  } else {
    if (t < 32){
      int s = t >> 3, h = t & 7;
      const float* br = bk + s*256 + h*32;
      const float* q = pq + t*32;
      float a = 0.f;
#pragma unroll
      for (int j=0;j<32;j++) a = fmaf(br[j], q[j], a);
      ws[CQ_OFF + t] = a*scale;
    }
    for (int i = t; i < 352; i += 256) ws[PS_OFF + i] = 0.f;   // zero atomic targets
  }
}

// ---- KBD10: MFMA scores + exp + PS atomics + MFMA xw chunk partials.
// 521 blocks x 512 threads. Pass1 = R12-proven. Pass2 = MFMA with
// A = swT[sh][j] (bf16 weights) and B = x via ds_read_b64_tr_b16.
__global__ __launch_bounds__(512,4) void kbd10(const float* __restrict__ x, float* __restrict__ ws){
  int b = blockIdx.x, t = threadIdx.x;
  int c  = (b < 520) ? (b / CPC) : 10;
  int wi = (b < 520) ? (b % CPC) : 0;
  int n0 = c*CS + wi*64;
  int n1 = min(n0 + 64, min((c+1)*CS, N));
  int cnt = n1 - n0;                    // 64, 12 (cluster tails), or 8 (cluster 10)

  __shared__ __align__(16) unsigned short xtb[64*264]; // 33.8KB bf16 tile, row stride 528B
  __shared__ __align__(16) unsigned short swT[32*72];  // 4.6KB bf16 weights [sh][j], stride 144B
  __shared__ float psb[16*32];

  int wv = t >> 6, lane = t & 63;
  int Mt = wv & 3, Nt = wv >> 2;
  int l15 = lane & 15, kg = lane >> 4;
  int arow = Mt*16 + l15;
  uint4 bfr[8];
  const uint4* WQBF4 = (const uint4*)(ws + WQBF_OFF);
#pragma unroll
  for (int ks=0; ks<8; ++ks) bfr[ks] = WQBF4[(size_t)(Nt*8 + ks)*64 + lane];
  float cqv = ws[CQ_OFF + Nt*16 + l15];
  int shc = Nt*16 + l15;

  // stage 64 rows as bf16; rows >= N zero-filled (NaN-safe for pass2 MFMA)
  const float4* X4 = (const float4*)x;
#pragma unroll
  for (int k=0;k<8;k++){
    int f = t + k*512;
    int j = f >> 6, c4 = f & 63;
    float4 v = (n0 + j < N) ? X4[(size_t)(n0+j)*64 + c4] : make_float4(0.f,0.f,0.f,0.f);
    uint2 p;
    p.x = f2bf(v.x) | (f2bf(v.y) << 16);
    p.y = f2bf(v.z) | (f2bf(v.w) << 16);
    *(uint2*)(xtb + j*264 + c4*4) = p;
  }
  __syncthreads();

  // ---- pass 1: scores via 8x mfma_f32_16x16x32_bf16 (R12-proven)
  f32x4 acc1 = {0.f, 0.f, 0.f, 0.f};
#pragma unroll
  for (int ks=0; ks<8; ++ks){
    union { uint4 q; short8 v; } A, B;
    A.q = *(const uint4*)(xtb + arow*264 + ks*32 + kg*8);
    B.q = bfr[ks];
    acc1 = __builtin_amdgcn_mfma_f32_16x16x32_bf16(A.v, B.v, acc1, 0, 0, 0);
  }
  // epilogue: weights (bf16) -> swT[sh][j]; zero for j >= cnt; chunk sums.
  // C layout: col(sh)=lane&15, row(j)=kg*4+reg.
  {
    float ev[4];
    float s4 = 0.f;
#pragma unroll
    for (int r=0;r<4;r++){
      int jl = Mt*16 + kg*4 + r;
      float e = (jl < cnt) ? __expf(acc1[r] + cqv) : 0.f;
      ev[r] = e; s4 += e;
    }
    uint2 wp;
    wp.x = f2bf(ev[0]) | (f2bf(ev[1]) << 16);
    wp.y = f2bf(ev[2]) | (f2bf(ev[3]) << 16);
    *(uint2*)(swT + (size_t)shc*72 + Mt*16 + kg*4) = wp;
    psb[(Mt*4 + kg)*32 + shc] = s4;
  }
  __syncthreads();
  if (t < 32){
    float S = 0.f;
#pragma unroll
    for (int k=0;k<16;k++) S += psb[k*32 + t];
    unsafeAtomicAdd(ws + PS_OFF + (size_t)c*32 + t, S);
  }

  // ---- pass 2: O[sh][d] = sum_j w[j][sh]*x[j][d] via MFMA.
  // wave -> Mt2 = wv&1 (sh-tile), Nq = wv>>1 (4 d-tiles Nt = Nq*4+i).
  int Mt2 = wv & 1, Nq = wv >> 1;
  union FR { uint4 q; short8 v; };
  FR a0, a1;   // A-fragments: lane m = l15 (sh), k = ks2*32 + kg*8 + e (j)
  a0.q = *(const uint4*)(swT + (size_t)(Mt2*16 + l15)*72 + kg*8);
  a1.q = *(const uint4*)(swT + (size_t)(Mt2*16 + l15)*72 + 32 + kg*8);
  // B via HW transpose read: input lane l loads 4 consecutive d (8B) at
  // row j0+8g+(l15>>2), col Nt*16+4*(l15&3); crossbar delivers
  // lane l elems e = x[j0+8g+e][Nt*16+l15]  (m156/m162 semantics).
  unsigned xb = (unsigned)(size_t)&xtb[0];
  unsigned va = xb + (unsigned)(kg*4224 + (l15>>2)*528 + (l15&3)*8 + Nq*128);
  unsigned long long tr[4][2][2];
#pragma unroll
  for (int i=0;i<4;i++){
#pragma unroll
    for (int k2=0;k2<2;k2++){
      asm volatile("ds_read_b64_tr_b16 %0, %2 offset:%c3\n\t"
                   "ds_read_b64_tr_b16 %1, %2 offset:%c4"
                   : "=v"(tr[i][k2][0]), "=v"(tr[i][k2][1])
                   : "v"(va), "i"(i*32 + k2*16896), "i"(i*32 + k2*16896 + 2112));
    }
  }
  asm volatile("s_waitcnt lgkmcnt(0)" ::: "memory");
  __builtin_amdgcn_sched_barrier(0);
  f32x4 o[4] = {{0.f,0.f,0.f,0.f},{0.f,0.f,0.f,0.f},{0.f,0.f,0.f,0.f},{0.f,0.f,0.f,0.f}};
#pragma unroll
  for (int i=0;i<4;i++){
#pragma unroll
    for (int k2=0;k2<2;k2++){
      FR Bf;
      Bf.q.x = (unsigned)(tr[i][k2][0] & 0xffffffffULL);
      Bf.q.y = (unsigned)(tr[i][k2][0] >> 32);
      Bf.q.z = (unsigned)(tr[i][k2][1] & 0xffffffffULL);
      Bf.q.w = (unsigned)(tr[i][k2][1] >> 32);
      o[i] = __builtin_amdgcn_mfma_f32_16x16x32_bf16(k2 ? a1.v : a0.v, Bf.v, o[i], 0, 0, 0);
    }
  }
  // store partials: C layout col(d)=l15, row(sh)=kg*4+r
  float* pr = ws + PART_OFF + (size_t)b*8192;
#pragma unroll
  for (int i=0;i<4;i++){
    int dcol = Nq*64 + i*16 + l15;
#pragma unroll
    for (int r=0;r<4;r++)
      pr[(size_t)(Mt2*16 + kg*4 + r)*256 + dcol] = o[i][r];
  }
}

// ---- KE2: sum chunk partials / PS -> xw[c][sh][d]. 352 blocks (R7-proven).
__global__ __launch_bounds__(256) void ke2(float* __restrict__ ws){
  int b = blockIdx.x, t = threadIdx.x;
  int c = b >> 5, sh = b & 31;
  int nch = (c < 10) ? CPC : 1;
  int cb  = (c < 10) ? c*CPC : 520;
  float rden = 1.0f / ws[PS_OFF + (size_t)c*32 + sh];
  const float* part = ws + PART_OFF + (size_t)sh*256 + t;
  float a = 0.f;
  for (int k=0;k<nch;k++) a += part[(size_t)(cb+k)*8192];
  ws[XW_OFF + (size_t)c*8192 + (size_t)sh*256 + t] = a * rden;
}

// ---- KP: pooled per (c,s,eq). 176 blocks (R7-proven).
__global__ __launch_bounds__(256) void kp(float* __restrict__ ws,
    const float* __restrict__ Wv, const float* __restrict__ bv){
  int b = blockIdx.x; int c = b >> 4, rem = b & 15, s = rem >> 2, eq = rem & 3;
  int t = threadIdx.x, e64 = t & 63, dq = t >> 6;
  int e = eq*64 + e64, h = e >> 5;
  const float* xr = ws + XW_OFF + (size_t)c*8192 + (size_t)(s*8 + h)*256 + dq*64;
  const float* wv = Wv + (size_t)s*65536 + (size_t)(dq*64)*256 + e;
  float a = 0.f;
#pragma unroll 8
  for (int d=0; d<64; ++d) a = fmaf(wv[(size_t)d*256], xr[d], a);
  __shared__ float red[4][64];
  red[dq][e64] = a;
  __syncthreads();
  if (t < 64){
    float rcnt = (c < 10) ? (1.0f/(float)CS) : 0.125f;
    float p = (red[0][t]+red[1][t]+red[2][t]+red[3][t] + bv[s*256 + eq*64 + t]) * rcnt;
    ws[PL_OFF + (size_t)c*1024 + s*256 + eq*64 + t] = p;
  }
}

// ---- KO: out per (c,s,eq) = pooled @ Wo + bo. 176 blocks (R7-proven).
__global__ __launch_bounds__(256) void ko(float* __restrict__ ws,
    const float* __restrict__ Wo, const float* __restrict__ bo){
  int b = blockIdx.x; int c = b >> 4, rem = b & 15, s = rem >> 2, eq = rem & 3;
  int t = threadIdx.x, e64 = t & 63, dq = t >> 6;
  int e = eq*64 + e64;
  const float* pr = ws + PL_OFF + (size_t)c*1024 + s*256 + dq*64;
  const float* wo = Wo + (size_t)s*65536 + (size_t)(dq*64)*256 + e;
  float a = 0.f;
#pragma unroll 8
  for (int d=0; d<64; ++d) a = fmaf(wo[(size_t)d*256], pr[d], a);
  __shared__ float red[4][64];
  red[dq][e64] = a;
  __syncthreads();
  if (t < 64)
    ws[OL_OFF + (size_t)c*1024 + s*256 + eq*64 + t] =
      red[0][t]+red[1][t]+red[2][t]+red[3][t] + bo[s*256 + eq*64 + t];
}

// ---- KF1: h partials: block (c, fq, kq). 176 blocks (R7-proven).
__global__ __launch_bounds__(256) void kf1(const float* __restrict__ Wf1, float* __restrict__ ws){
  int b = blockIdx.x; int c = b >> 4, fq = (b >> 2) & 3, kq = b & 3;
  int t = threadIdx.x, f64 = t & 63, ks = t >> 6;
  const float* ol = ws + OL_OFF + (size_t)c*1024 + kq*256 + ks*64;
  const float* wf = Wf1 + (size_t)(kq*256 + ks*64)*256 + fq*64 + f64;
  float a = 0.f;
#pragma unroll 8
  for (int i=0; i<64; ++i) a = fmaf(wf[(size_t)i*256], ol[i], a);
  __shared__ float red[4][64];
  red[ks][f64] = a;
  __syncthreads();
  if (t < 64)
    ws[HP_OFF + (size_t)(c*4 + kq)*256 + fq*64 + t] = red[0][t]+red[1][t]+red[2][t]+red[3][t];
}

// ---- KF2B: (LN+GELU recomputed in-block from HP) -> Wf2 partials. 176 blocks (R11-proven).
__global__ __launch_bounds__(256) void kf2b(const float* __restrict__ Wf2, float* __restrict__ ws,
    const float* __restrict__ bf1, const float* __restrict__ lng, const float* __restrict__ lnb){
  int b = blockIdx.x; int c = b >> 4, gq = (b >> 2) & 3, kq = b & 3;
  int t = threadIdx.x;
  __shared__ float hl[256];
  __shared__ float rs1[4], rs2[4];
  float hacc = bf1[t];
#pragma unroll
  for (int q=0;q<4;q++) hacc += ws[HP_OFF + (size_t)(c*4+q)*256 + t];
  float s1 = hacc, s2v = hacc*hacc;
  for (int off=32; off>0; off>>=1){ s1 += __shfl_down(s1, off, 64); s2v += __shfl_down(s2v, off, 64); }
  int wid = t>>6, lane = t&63;
  if (lane==0){ rs1[wid]=s1; rs2[wid]=s2v; }
  __syncthreads();
  float S1 = rs1[0]+rs1[1]+rs1[2]+rs1[3];
  float S2 = rs2[0]+rs2[1]+rs2[2]+rs2[3];
  float mu = S1*(1.0f/256.0f);
  float var = S2*(1.0f/256.0f) - mu*mu;
  float rsig = rsqrtf(var + 1e-5f);
  float hn = (hacc - mu)*rsig*lng[t] + lnb[t];
  hl[t] = 0.5f*hn*(1.0f + erff(hn*0.70710678118654752f));   // exact GELU
  __syncthreads();
  int g64 = t & 63, ks = t >> 6;
  const float* hh = hl + kq*64 + ks*16;
  const float* wf = Wf2 + (size_t)(kq*64 + ks*16)*256 + gq*64 + g64;
  float a = 0.f;
#pragma unroll
  for (int i=0; i<16; ++i) a = fmaf(wf[(size_t)i*256], hh[i], a);
  __shared__ float red[4][64];
  red[ks][g64] = a;
  __syncthreads();
  if (t < 64)
    ws[FP_OFF + (size_t)(c*4 + kq)*256 + gq*64 + t] = red[0][t]+red[1][t]+red[2][t]+red[3][t];
}

// ---- KBC2: sum Wf2 partials + bf2 once per block, broadcast. 8192 blocks (R7-proven).
__global__ __launch_bounds__(256) void kbc2(const float* __restrict__ ws, float4* __restrict__ out,
                                            const float* __restrict__ bf2){
  unsigned bidx = blockIdx.x, t = threadIdx.x;
  unsigned idx = bidx*256u + t;
  unsigned c = (bidx*4u) / (unsigned)CS;   // 3276 % 4 == 0 -> one cluster per block
  __shared__ float4 row[64];
  if (t < 64){
    const float4* FP4 = (const float4*)(ws + FP_OFF);
    float4 s0 = FP4[(c*4+0)*64 + t];
    float4 s1 = FP4[(c*4+1)*64 + t];
    float4 s2 = FP4[(c*4+2)*64 + t];
    float4 s3 = FP4[(c*4+3)*64 + t];
    float4 bb = ((const float4*)bf2)[t];
    row[t] = make_float4(s0.x+s1.x+s2.x+s3.x+bb.x, s0.y+s1.y+s2.y+s3.y+bb.y,
                         s0.z+s1.z+s2.z+s3.z+bb.z, s0.w+s1.w+s2.w+s3.w+bb.w);
  }
  __syncthreads();
  out[idx] = row[t & 63u];
}

extern "C" void kernel_launch(void* const* d_in, const int* in_sizes, int n_in,
                              void* d_out, int out_size, void* d_ws, size_t ws_size,
                              hipStream_t stream) {
  const float* x   = (const float*)d_in[0];
  // d_in[1] edge_index, d_in[2] batch: unused by the reference computation
  const float* Wk  = (const float*)d_in[3];
  const float* bk  = (const float*)d_in[4];
  const float* Wv  = (const float*)d_in[5];
  const float* bv  = (const float*)d_in[6];
  const float* Wo  = (const float*)d_in[7];
  const float* bo  = (const float*)d_in[8];
  const float* pq  = (const float*)d_in[9];
  const float* Wf1 = (const float*)d_in[10];
  const float* bf1 = (const float*)d_in[11];
  const float* lng = (const float*)d_in[12];
  const float* lnb = (const float*)d_in[13];
  const float* Wf2 = (const float*)d_in[14];
  const float* bf2 = (const float*)d_in[15];
  float* ws = (float*)d_ws;
  float4* out = (float4*)d_out;

  hipLaunchKernelGGL(ka,    dim3(33),   dim3(256), 0, stream, Wk, bk, pq, ws);
  hipLaunchKernelGGL(kbd10, dim3(NB),   dim3(512), 0, stream, x, ws);
  hipLaunchKernelGGL(ke2,   dim3(352),  dim3(256), 0, stream, ws);
  hipLaunchKernelGGL(kp,    dim3(176),  dim3(256), 0, stream, ws, Wv, bv);
  hipLaunchKernelGGL(ko,    dim3(176),  dim3(256), 0, stream, ws, Wo, bo);
  hipLaunchKernelGGL(kf1,   dim3(176),  dim3(256), 0, stream, Wf1, ws);
  hipLaunchKernelGGL(kf2b,  dim3(176),  dim3(256), 0, stream, Wf2, ws, bf1, lng, lnb);
  hipLaunchKernelGGL(kbc2,  dim3(8192), dim3(256), 0, stream, ws, out, bf2);
}